// Round 9
// baseline (432.275 us; speedup 1.0000x reference)
//
#include <hip/hip_runtime.h>

#define B_SZ 2048
#define T_SZ 2048

using f32x16 = float __attribute__((ext_vector_type(16)));
using f32x2  = float __attribute__((ext_vector_type(2)));

// DPP move: result[lane] = src[perm(lane)] (quad_perm / row_ror patterns)
template<int CTRL>
__device__ __forceinline__ float dppf(float v) {
  int r = __builtin_amdgcn_update_dpp(0, __builtin_bit_cast(int, v), CTRL, 0xf, 0xf, true);
  return __builtin_bit_cast(float, r);
}

// packed butterfly stage: v += dpp<CTRL>(v), elementwise on both halves
template<int CTRL>
__device__ __forceinline__ f32x2 bstage(f32x2 v) {
  f32x2 s;
  s[0] = dppf<CTRL>(v[0]);
  s[1] = dppf<CTRL>(v[1]);
  return v + s;
}

__device__ __forceinline__ f32x2 pkfma(f32x2 a, f32x2 b, f32x2 c) {
  return __builtin_elementwise_fma(a, b, c);
}

// 4 batch rows per wave: 16-lane group = row; lane owns units sl,sl+16,sl+32,sl+48.
// Reduce: 16-lane ALL-REDUCE butterfly (xor1, xor2, ror4, ror8) on packed
// per-channel partials -> every lane holds all 4 channel sums; x kept local
// per lane (no broadcast, no y cross-lane reduce, zero DS on the chain).
__global__ __launch_bounds__(256, 1) void sss_kernel(
    const float* __restrict__ x0p, const float* __restrict__ up,
    const float* __restrict__ tfp, const float* __restrict__ thp,
    const float* __restrict__ tup, const float* __restrict__ typ,
    const float* __restrict__ W1p, const float* __restrict__ b1p,
    const float* __restrict__ W2p, const float* __restrict__ Whp,
    float* __restrict__ outp)
{
  const int lane = threadIdx.x & 63;
  const int wv   = __builtin_amdgcn_readfirstlane((int)(threadIdx.x >> 6));
  const int grp  = lane >> 4;              // 16-lane group = row within wave
  const int sl   = lane & 15;              // sub-lane within group
  const int b    = blockIdx.x * 16 + wv * 4 + grp;   // batch row

  // ---- prologue ----
  // fold K = 2*log2(e) into W1/cc: tanh(a) = 1 - 2/(exp2(K*a)+1)
  const float K = 2.8853900817779268f;
  // unit pairs packed as f32x2: _01 = units (sl, sl+16), _23 = (sl+32, sl+48)
  f32x2 w1_01[6], w1_23[6];
#pragma unroll
  for (int r = 0; r < 6; ++r) {
    w1_01[r] = f32x2{W1p[r * 64 + sl]      * K, W1p[r * 64 + sl + 16] * K};
    w1_23[r] = f32x2{W1p[r * 64 + sl + 32] * K, W1p[r * 64 + sl + 48] * K};
  }
  float ccs[4];
#pragma unroll
  for (int i = 0; i < 4; ++i) {
    const int u = sl + 16 * i;
    float t = b1p[u];
#pragma unroll
    for (int q = 0; q < 5; ++q) t = fmaf(tfp[q], W1p[(6 + q) * 64 + u], t);
    ccs[i] = t * K;
  }
  const f32x2 cc01 = f32x2{ccs[0], ccs[1]};
  const f32x2 cc23 = f32x2{ccs[2], ccs[3]};

  const float scale = tup[0] / typ[0];
  // W2 column pairs per unit i: c01[i] = {W2[u][0],W2[u][1]}, c23[i] = {W2[u][2],W2[u][3]}
  f32x2 c01[4], c23[4];
#pragma unroll
  for (int i = 0; i < 4; ++i) {
    const float4 w2r = ((const float4*)W2p)[sl + 16 * i];
    c01[i] = f32x2{w2r.x * scale, w2r.y * scale};
    c23[i] = f32x2{w2r.z * scale, w2r.w * scale};
  }

  const float wh0 = Whp[0], wh1 = Whp[1], wh2 = Whp[2], wh3 = Whp[3];
  const float th  = thp[0];

  // per-lane local state: all 4 components, packed
  f32x2 x01 = f32x2{x0p[b * 4 + 0], x0p[b * 4 + 1]};
  f32x2 x23 = f32x2{x0p[b * 4 + 2], x0p[b * 4 + 3]};

  // y0 = h(x_0), UNCLAMPED (matches reference)
  float yv = fmaf(x01[0], wh0, fmaf(x01[1], wh1, fmaf(x23[0], wh2, fmaf(x23[1], wh3, th))));

  // ---- per-step direct output store setup ----
  // per group: sub-lanes 0-3 -> outx[b][t][sl]; sub-lane 4 -> outy[b][t]
  unsigned voff, vinc;
  if (sl < 4) {
    voff = (unsigned)(b * (T_SZ * 4) + sl) * 4u;
    vinc = 16u;
  } else {
    voff = (unsigned)((unsigned)B_SZ * T_SZ * 4u + (unsigned)b * T_SZ) * 4u;
    vinc = (sl == 4) ? 4u : 0u;
  }
  const bool doSt = (sl < 5);
  const bool is4  = (sl == 4);
  const bool s1   = sl & 1;
  const bool s2   = sl & 2;

  const f32x16* up16 = (const f32x16*)(up + (size_t)b * (T_SZ * 2)); // 8 steps/chunk
  char* outB = (char*)outp;

  f32x16 uch = up16[0];
  const int NC = T_SZ / 8;

  for (int c = 0; c < NC; ++c) {
    const int g = (c + 1 < NC) ? c + 1 : NC - 1;   // prefetch next chunk
    const f32x16 unx = up16[g];
#pragma unroll
    for (int jj = 0; jj < 8; ++jj) {
      // ---- emit PRE-update carry (x_step, y_step) ----
      const float t0 = s1 ? x01[1] : x01[0];
      const float t1 = s1 ? x23[1] : x23[0];
      const float td = s2 ? t1 : t0;
      const float vdata = is4 ? yv : td;
      if (doSt) *(float*)(outB + voff) = vdata;
      voff += vinc;

      const float u0 = uch[2 * jj];
      const float u1 = uch[2 * jj + 1];
      const f32x2 u0p = f32x2{u0, u0};
      const f32x2 u1p = f32x2{u1, u1};

      // u-only part (x-independent, schedulable early), packed unit pairs
      const f32x2 b01 = pkfma(u1p, w1_01[5], pkfma(u0p, w1_01[4], cc01));
      const f32x2 b23 = pkfma(u1p, w1_23[5], pkfma(u0p, w1_23[4], cc23));

      // x-part: depth-3, packed (x splats fold into pk op_sel)
      const f32x2 x0s = f32x2{x01[0], x01[0]};
      const f32x2 x1s = f32x2{x01[1], x01[1]};
      const f32x2 x2s = f32x2{x23[0], x23[0]};
      const f32x2 x3s = f32x2{x23[1], x23[1]};
      const f32x2 mA01 = pkfma(x1s, w1_01[1], x0s * w1_01[0]);
      const f32x2 mB01 = pkfma(x3s, w1_01[3], x2s * w1_01[2]);
      const f32x2 a01  = (b01 + mA01) + mB01;
      const f32x2 mA23 = pkfma(x1s, w1_23[1], x0s * w1_23[0]);
      const f32x2 mB23 = pkfma(x3s, w1_23[3], x2s * w1_23[2]);
      const f32x2 a23  = (b23 + mA23) + mB23;

      // tanh(a) = 1 - 2/(exp2(acc)+1), 4 units
      float h[4];
      {
        const float av[4] = {a01[0], a01[1], a23[0], a23[1]};
#pragma unroll
        for (int i = 0; i < 4; ++i) {
          const float e  = __builtin_amdgcn_exp2f(av[i]);
          const float rr = __builtin_amdgcn_rcpf(e + 1.0f);
          h[i] = fmaf(-2.0f, rr, 1.0f);
        }
      }
      const f32x2 h0s = f32x2{h[0], h[0]};
      const f32x2 h1s = f32x2{h[1], h[1]};
      const f32x2 h2s = f32x2{h[2], h[2]};
      const f32x2 h3s = f32x2{h[3], h[3]};

      // per-lane per-channel partials (tree, depth 3)
      f32x2 p01 = pkfma(h1s, c01[1], h0s * c01[0]) + pkfma(h3s, c01[3], h2s * c01[2]);
      f32x2 p23 = pkfma(h1s, c23[1], h0s * c23[0]) + pkfma(h3s, c23[3], h2s * c23[2]);

      // 16-lane ALL-REDUCE butterfly: xor1, xor2, ror4, ror8 (4 DPP stages)
      p01 = bstage<0xB1>(p01);  p23 = bstage<0xB1>(p23);
      p01 = bstage<0x4E>(p01);  p23 = bstage<0x4E>(p23);
      p01 = bstage<0x124>(p01); p23 = bstage<0x124>(p23);
      p01 = bstage<0x128>(p01); p23 = bstage<0x128>(p23);

      // update: w = pre-clip x_raw (every lane has all 4 components)
      const f32x2 w01 = x01 + p01;
      const f32x2 w23 = x23 + p23;

      // y from PRE-clip state (local, no cross-lane)
      const float yy = fmaf(w01[0], wh0, fmaf(w01[1], wh1, fmaf(w23[0], wh2, w23[1] * wh3)));
      yv = __builtin_amdgcn_fmed3f(yy + th, 0.0f, 10.0f);

      // clip: channels 0..2 -> [0,10], channel 3 unbounded
      x01 = f32x2{__builtin_amdgcn_fmed3f(w01[0], 0.0f, 10.0f),
                  __builtin_amdgcn_fmed3f(w01[1], 0.0f, 10.0f)};
      x23 = f32x2{__builtin_amdgcn_fmed3f(w23[0], 0.0f, 10.0f), w23[1]};
    }
    uch = unx;
  }
}

extern "C" void kernel_launch(void* const* d_in, const int* in_sizes, int n_in,
                              void* d_out, int out_size, void* d_ws, size_t ws_size,
                              hipStream_t stream) {
  (void)in_sizes; (void)n_in; (void)out_size; (void)d_ws; (void)ws_size;
  sss_kernel<<<dim3(B_SZ / 16), dim3(256), 0, stream>>>(
      (const float*)d_in[0], (const float*)d_in[1], (const float*)d_in[2],
      (const float*)d_in[3], (const float*)d_in[4], (const float*)d_in[5],
      (const float*)d_in[6], (const float*)d_in[7], (const float*)d_in[8],
      (const float*)d_in[9], (float*)d_out);
}